// Round 15
// baseline (178.905 us; speedup 1.0000x reference)
//
#include <hip/hip_runtime.h>
#include <hip/hip_fp16.h>

typedef unsigned long long u64;
typedef unsigned int uint32;
typedef short short8 __attribute__((ext_vector_type(8)));
typedef float f32x4 __attribute__((ext_vector_type(4)));
typedef _Float16 h2 __attribute__((ext_vector_type(2)));

#define B_N 8192
#define L_N 1024
#define M_N 128
#define HALF_N 512

// ws layout (bytes)
#define OFF_WS   0x0         // wshr[u][3][128] fp16 {wE, re-1, ro-1}: 384KB
#define OFF_WSEL 0x60000     // wsel[u][2][128] fp16 {wo, wo*re}: 256KB
#define OFF_LR   0xA0000     // lrT[m][t] bf16: 256KB
#define OFF_BITS 0xE0000     // bits[b][16] u64: 1MB
#define OFF_T    0x1E0000    // T[b] int32: 32KB
#define OFF_RQ   0x200000    // Rq[cn][b][m] fp16: 32MB (cn=16) or 64MB (cn=32)

#define PACK_BLK 2048
#define PACK_IT  16          // 2048*256*16 = B*L
#define EPS_BLK  32
#define ZERO_BLK 32

__device__ __forceinline__ unsigned short f32_bf16(float f) {
    union { float f; unsigned u; } x; x.f = f;
    unsigned u = x.u + 0x7FFFu + ((x.u >> 16) & 1u);   // RNE
    return (unsigned short)(u >> 16);
}

__device__ __forceinline__ float fdot2(h2 a, h2 b, float c) {
#if __has_builtin(__builtin_amdgcn_fdot2)
    return __builtin_amdgcn_fdot2(a, b, c, false);
#else
    return (float)a[0] * (float)b[0] + (float)a[1] * (float)b[1] + c;
#endif
}

__device__ __forceinline__ uint32 fas_u(float f) { union { float f; uint32 u; } x; x.f = f; return x.u; }
__device__ __forceinline__ float uas_f(uint32 u) { union { uint32 u; float f; } x; x.u = u; return x.f; }

__device__ __forceinline__ float exp2_n(float x) {
#if __has_builtin(__builtin_amdgcn_exp2f)
    return __builtin_amdgcn_exp2f(x);
#else
    return exp2f(x);
#endif
}
__device__ __forceinline__ float log2_n(float x) {
#if __has_builtin(__builtin_amdgcn_logf)
    return __builtin_amdgcn_logf(x);
#else
    return __log2f(x);
#endif
}
// sign-extended single-bit extract: 0 or 0xFFFFFFFF
__device__ __forceinline__ uint32 bfe1(uint32 v, int off) {
#if __has_builtin(__builtin_amdgcn_sbfe)
    return (uint32)__builtin_amdgcn_sbfe((int)v, off, 1);
#else
    return (uint32)((int)(v << (31 - off)) >> 31);
#endif
}

// x + dpp(y). CTRL: 0xB1 = quad_perm[1,0,3,2], 0x4E = quad_perm[2,3,0,1],
// 0x104 = row_shl:4 — all HW-proven in r3/r4/r5.
template<int CTRL>
__device__ __forceinline__ float dpp_add(float x, float y) {
    union { float f; int i; } a, r;
    a.f = y;
    r.i = __builtin_amdgcn_update_dpp(0, a.i, CTRL, 0xF, 0xF, true);
    return x + r.f;
}

union HU { uint32 u; __half2 hh; h2 v2; };

// ---- K0: fused prep: spin-pack | pair tables (fp16) | zero out ----------
__global__ __launch_bounds__(256) void k_prep(const int* __restrict__ inp,
        const float* __restrict__ eps, u64* __restrict__ bits,
        _Float16* __restrict__ wshr, _Float16* __restrict__ wsel,
        unsigned short* __restrict__ lrT, float* __restrict__ out) {
    int bid = blockIdx.x;
    if (bid < PACK_BLK) {
        int g = bid * 256 + threadIdx.x;
        const int stride = PACK_BLK * 256;
        #pragma unroll 4
        for (int it = 0; it < PACK_IT; ++it) {
            int v = inp[g];
            u64 m = __ballot(v != 0);
            if ((threadIdx.x & 63) == 0) bits[g >> 6] = m;
            g += stride;
        }
        return;
    }
    bid -= PACK_BLK;
    if (bid < EPS_BLK) {
        int wid = threadIdx.x >> 6, lane = threadIdx.x & 63;
        int m = bid * 4 + wid;
        const float* e0 = eps + (size_t)m * L_N + lane * 16;
        const float* e1 = eps + (size_t)(M_N + m) * L_N + lane * 16;
        float a[16], b[16];
        #pragma unroll
        for (int j = 0; j < 16; j += 4) {
            *(float4*)&a[j] = *(const float4*)&e0[j];
            *(float4*)&b[j] = *(const float4*)&e1[j];
        }
        float local = 1.f;
        #pragma unroll
        for (int j = 0; j < 16; ++j) local *= a[j];
        float sc = local;
        #pragma unroll
        for (int d = 1; d < 64; d <<= 1) {
            float up = __shfl_up(sc, d);
            if (lane >= d) sc *= up;
        }
        float prev = __shfl_up(sc, 1);
        float E = (lane == 0) ? 1.f : prev;
        int i0 = lane * 16;
        float rat_e = 1.f, w_e = 0.f;
        #pragma unroll
        for (int j = 0; j < 16; ++j) {
            float rat = b[j] / a[j];
            float w = E * (a[j] - b[j]);
            lrT[(size_t)m * L_N + i0 + j] = f32_bf16(__log2f(rat));
            int u = (i0 + j) >> 1;
            if ((j & 1) == 0) {
                rat_e = rat; w_e = w;
            } else {
                // shared rows {wE, re-1, ro-1}
                _Float16* wr = wshr + (size_t)u * 384;
                wr[m]       = (_Float16)w_e;
                wr[128 + m] = (_Float16)(rat_e - 1.f);
                wr[256 + m] = (_Float16)(rat - 1.f);
                // selected odd-weight rows {wo, wo*re} (bit_e selects)
                _Float16* ws = wsel + (size_t)u * 256;
                ws[m]       = (_Float16)w;
                ws[128 + m] = (_Float16)(w * rat_e);
            }
            E *= a[j];
        }
        return;
    }
    bid -= EPS_BLK;
    if (bid < ZERO_BLK) {
        out[bid * 256 + threadIdx.x] = 0.f;
    }
}

// ---- K2: MFMA chunk log-sums + f32 cumsum + exp2 -> fp16 excl prefix ----
// blocks [0,1024): prefix at CN granularity; [1024,1056): saturation T.
template<int CN>
__global__ __launch_bounds__(256) void k_slog2(const u64* __restrict__ bits,
        const unsigned short* __restrict__ lrT, _Float16* __restrict__ Rq,
        int* __restrict__ T) {
    if (blockIdx.x >= 1024) {
        int b = (blockIdx.x - 1024) * 256 + threadIdx.x;
        const u64* brow = bits + (size_t)b * 16;
        int n1 = 0, n0 = 0, Tv = 1024;
        for (int wd = 0; wd < 16; ++wd) {
            u64 x = brow[wd];
            int pc = __popcll(x);
            if (n1 + pc < HALF_N && n0 + (64 - pc) < HALF_N) {
                n1 += pc; n0 += 64 - pc;
                continue;
            }
            int found = 0;
            for (int k = 0; k < 64; ++k) {
                if (n1 >= HALF_N || n0 >= HALF_N) { Tv = wd * 64 + k; found = 1; break; }
                int sb = (int)((x >> k) & 1);
                n1 += sb; n0 += 1 - sb;
            }
            if (!found) Tv = (wd + 1) * 64;
            break;
        }
        T[b] = Tv;
        return;
    }
    int btile = blockIdx.x >> 1;
    int half = blockIdx.x & 1;
    int wid = threadIdx.x >> 6, lane = threadIdx.x & 63;
    int col = lane & 15, quad = lane >> 4;
    int m = (half * 4 + wid) * 16 + col;
    int b_row = btile * 16 + col;
    const u64* brow = bits + (size_t)b_row * 16;
    const unsigned short* lrow = lrT + (size_t)m * L_N;

    f32x4 cum = (f32x4){0.f, 0.f, 0.f, 0.f};

    for (int w = 0; w < 16; ++w) {
        u64 wv = brow[w];
        #pragma unroll
        for (int hf = 0; hf < 2; ++hf) {
            if (CN == 32 || hf == 0) {
                int cc = (CN == 32) ? (w * 2 + hf) : w;
                #pragma unroll
                for (int reg = 0; reg < 4; ++reg) {
                    int b = btile * 16 + quad * 4 + reg;
                    Rq[((size_t)cc * B_N + b) * M_N + m] = (_Float16)exp2_n(cum[reg]);
                }
            }
            short8 a;
            #pragma unroll
            for (int j = 0; j < 8; ++j)
                a[j] = (short)((((wv >> (hf * 32 + quad * 8 + j)) & 1) != 0) ? 0x3F80 : 0);
            union { uint4 u; short8 s; } bf;
            bf.u = *(const uint4*)(lrow + w * 64 + hf * 32 + quad * 8);
            cum = __builtin_amdgcn_mfma_f32_16x16x32_bf16(a, bf.s, cum, 0, 0, 0);
        }
    }
}

// ------- K3: main loop — pair-steps, factored update (shared rows) -------
// Update R *= (1+cmb[combo]) factors as (1+(re-1)&be)*(1+(ro-1)&bo): two
// masked pk_fma passes against b-INDEPENDENT rows re-1, ro-1 staged once
// per pair (4 shared b128) — removes R12's 8 data-dependent CMu reads and
// their bank conflicts. Only the odd-weight row (wo vs wo*re, bit_e) stays
// data-selected (8 b128/pair). DS/pair: 18 -> 14 b128.
template<int CN>
__global__ __launch_bounds__(256) __attribute__((amdgpu_waves_per_eu(1, 4)))
void k_main(const u64* __restrict__ bits, const _Float16* __restrict__ wshr,
        const _Float16* __restrict__ wsel, const _Float16* __restrict__ Rq,
        const int* __restrict__ T, float* __restrict__ out) {
    constexpr int CHN = L_N / CN;                // 64 or 32 steps per chunk
    constexpr int CSH = (CN == 16) ? 4 : 5;
    __shared__ _Float16 shbuf[16 * 384];         // 12KB {wE,re-1,ro-1}/pair
    __shared__ _Float16 selbuf[16 * 256];        // 8KB {wo, wo*re}/pair
    int c = blockIdx.x & (CN - 1);
    int bblk = blockIdx.x >> CSH;
    int lane = threadIdx.x & 63, wid = threadIdx.x >> 6;
    int s = lane & 7, grp = lane >> 3;
    int q = s & 3;
    int b0 = bblk * 128 + wid * 32 + grp * 4;

    // prefix load: R2[k][j] = packed pair for b0+(q^k), m = s*16+2j
    HU R2[4][8];
    u64 wb[4];
    const int word0 = (c * CHN) >> 6;            // u64 word holding this chunk
    const int hs0 = ((c * CHN) >> 5) & 1;        // starting 32-bit half
    #pragma unroll
    for (int k = 0; k < 4; ++k) {
        int b = b0 + (q ^ k);
        union { uint4 v[2]; uint32 w[8]; } P;
        const uint4* src = (const uint4*)(Rq + ((size_t)c * B_N + b) * M_N + s * 16);
        P.v[0] = src[0]; P.v[1] = src[1];
        #pragma unroll
        for (int j = 0; j < 8; ++j) R2[k][j].u = P.w[j];
        wb[k] = bits[(size_t)b * 16 + word0];
    }
    int Tb = T[b0 + q];

    const float LOG2E2 = 2.885390082f; // 2*log2(e)
    const float NHL2 = -0.3465735903f; // -0.5*ln2
    float sum = 0.f;
    #pragma unroll
    for (int h = 0; h < CHN / 32; ++h) {
        // stage phase h: 16 pairs (coalesced uint4, linear layouts)
        if (h) __syncthreads();
        {
            size_t pbase = (size_t)c * (CHN / 2) + h * 16;
            const uint4* ss = (const uint4*)(wshr + pbase * 384);
            const uint4* sl = (const uint4*)(wsel + pbase * 256);
            #pragma unroll
            for (int t = 0; t < 3; ++t)
                ((uint4*)shbuf)[threadIdx.x + t * 256] = ss[threadIdx.x + t * 256];
            #pragma unroll
            for (int t = 0; t < 2; ++t)
                ((uint4*)selbuf)[threadIdx.x + t * 256] = sl[threadIdx.x + t * 256];
        }
        __syncthreads();

        int sh = ((hs0 + h) & 1) * 32;
        uint32 wh[4];
        #pragma unroll
        for (int k = 0; k < 4; ++k) wh[k] = (uint32)(wb[k] >> sh);
        uint32 ows = ~wh[0];                   // own b's word; bit==0 -> flip sign
        int rel = Tb - (c * CHN + h * 32);
        uint32 vmask = (rel <= 0) ? 0u : ((rel >= 32) ? 0xFFFFFFFFu : ((1u << rel) - 1u));

        #pragma unroll 2
        for (int tt = 0; tt < 16; ++tt) {      // 16 pairs = 32 steps
            union U8 { uint4 q4[2]; uint32 w[8]; h2 v2[8]; __half2 hh[8]; };
            int bs = tt * 384 + s * 16;
            U8 WEu, REu, ROu;
            WEu.q4[0] = *(const uint4*)&shbuf[bs];
            WEu.q4[1] = *((const uint4*)&shbuf[bs] + 1);
            REu.q4[0] = *(const uint4*)&shbuf[bs + 128];
            REu.q4[1] = *((const uint4*)&shbuf[bs + 128] + 1);
            ROu.q4[0] = *(const uint4*)&shbuf[bs + 256];
            ROu.q4[1] = *((const uint4*)&shbuf[bs + 256] + 1);

            // even dots: shared wE
            float de[4];
            #pragma unroll
            for (int k = 0; k < 4; ++k) {
                float acc = 0.f;
                #pragma unroll
                for (int j = 0; j < 8; ++j) acc = fdot2(R2[k][j].v2, WEu.v2[j], acc);
                de[k] = acc;
            }
            // odd dots: bit_e-selected row {wo, wo*re}
            int pb = tt * 256 + s * 16;
            float dd[4];
            #pragma unroll
            for (int k = 0; k < 4; ++k) {
                U8 WOu;
                int ad = pb + (int)(bfe1(wh[k], 2 * tt) & 128u);
                WOu.q4[0] = *(const uint4*)&selbuf[ad];
                WOu.q4[1] = *((const uint4*)&selbuf[ad] + 1);
                float acc = 0.f;
                #pragma unroll
                for (int j = 0; j < 8; ++j) acc = fdot2(R2[k][j].v2, WOu.v2[j], acc);
                dd[k] = acc;
            }
            // butterflies (select-free via k-permute)
            float xe = dpp_add<0xB1>(de[0], de[1]);
            float ye = dpp_add<0xB1>(de[2], de[3]);
            float De = dpp_add<0x4E>(xe, ye);
            De = dpp_add<0x104>(De, De);
            float xo = dpp_add<0xB1>(dd[0], dd[1]);
            float yo = dpp_add<0xB1>(dd[2], dd[3]);
            float Do = dpp_add<0x4E>(xo, yo);
            Do = dpp_add<0x104>(Do, Do);

            // softplus x2 (steps 2tt, 2tt+1), fma-folded tail
            uint32 sg0 = bfe1(ows, 2 * tt) & 0x80000000u;
            float l0 = log2_n(1.f + exp2_n(LOG2E2 * uas_f(fas_u(De) ^ sg0)));
            sum = fmaf(NHL2, uas_f(fas_u(l0) & bfe1(vmask, 2 * tt)), sum);
            uint32 sg1 = bfe1(ows, 2 * tt + 1) & 0x80000000u;
            float l1 = log2_n(1.f + exp2_n(LOG2E2 * uas_f(fas_u(Do) ^ sg1)));
            sum = fmaf(NHL2, uas_f(fas_u(l1) & bfe1(vmask, 2 * tt + 1)), sum);

            // factored update: R *= (1+(re-1)&be) * (1+(ro-1)&bo)
            #pragma unroll
            for (int k = 0; k < 4; ++k) {
                uint32 mE = bfe1(wh[k], 2 * tt);
                uint32 mO = bfe1(wh[k], 2 * tt + 1);
                #pragma unroll
                for (int j = 0; j < 8; ++j) {
                    HU se; se.u = REu.w[j] & mE;
                    R2[k][j].hh = __hfma2(se.hh, R2[k][j].hh, R2[k][j].hh);
                    HU so; so.u = ROu.w[j] & mO;
                    R2[k][j].hh = __hfma2(so.hh, R2[k][j].hh, R2[k][j].hh);
                }
            }
        }
    }
    if (s < 4) atomicAdd(&out[b0 + s], sum);
}

extern "C" void kernel_launch(void* const* d_in, const int* in_sizes, int n_in,
                              void* d_out, int out_size, void* d_ws, size_t ws_size,
                              hipStream_t stream) {
    const int*   inputs  = (const int*)d_in[0];     // (B, L) int32
    const float* epsilon = (const float*)d_in[1];   // (D, M, L) f32
    float* out = (float*)d_out;                     // (B,) f32

    char* ws = (char*)d_ws;
    _Float16* wshr = (_Float16*)(ws + OFF_WS);
    _Float16* wsel = (_Float16*)(ws + OFF_WSEL);
    unsigned short* lrT = (unsigned short*)(ws + OFF_LR);
    u64*   bits   = (u64*)  (ws + OFF_BITS);
    int*   T      = (int*)  (ws + OFF_T);
    _Float16* Rq  = (_Float16*)(ws + OFF_RQ);

    k_prep<<<PACK_BLK + EPS_BLK + ZERO_BLK, 256, 0, stream>>>(
        inputs, epsilon, bits, wshr, wsel, lrT, out);

    // CN=32 needs 64MB Rq; fall back to CN=16 if the workspace can't hold it.
    const size_t need32 = (size_t)OFF_RQ + (size_t)32 * B_N * M_N * 2;
    if (ws_size >= need32) {
        k_slog2<32><<<1024 + 32, 256, 0, stream>>>(bits, lrT, Rq, T);
        k_main<32><<<(B_N / 128) * 32, 256, 0, stream>>>(bits, wshr, wsel, Rq, T, out);
    } else {
        k_slog2<16><<<1024 + 32, 256, 0, stream>>>(bits, lrT, Rq, T);
        k_main<16><<<(B_N / 128) * 16, 256, 0, stream>>>(bits, wshr, wsel, Rq, T, out);
    }
}

// Round 16
// 163.820 us; speedup vs baseline: 1.0921x; 1.0921x over previous
//
#include <hip/hip_runtime.h>
#include <hip/hip_fp16.h>

typedef unsigned long long u64;
typedef unsigned int uint32;
typedef short short8 __attribute__((ext_vector_type(8)));
typedef float f32x4 __attribute__((ext_vector_type(4)));
typedef _Float16 h2 __attribute__((ext_vector_type(2)));

#define B_N 8192
#define L_N 1024
#define M_N 128
#define HALF_N 512

// ws layout (bytes)
#define OFF_WE   0x0         // wE[u][m] fp16, even-step weights: 128KB
#define OFF_CW   0x20000     // cw[u][4][256] fp16, [cmb|wO] super-rows: 1MB
#define OFF_LR   0x120000    // lrT[m][t] bf16: 256KB
#define OFF_BITS 0x160000    // bits[b][16] u64: 1MB
#define OFF_T    0x260000    // T[b] int32: 32KB
#define OFF_RQ   0x280000    // Rq[cn][b][m] fp16: 32MB (cn=16) or 64MB (cn=32)

#define PACK_BLK 2048
#define PACK_IT  16          // 2048*256*16 = B*L
#define EPS_BLK  32
#define ZERO_BLK 32

__device__ __forceinline__ unsigned short f32_bf16(float f) {
    union { float f; unsigned u; } x; x.f = f;
    unsigned u = x.u + 0x7FFFu + ((x.u >> 16) & 1u);   // RNE
    return (unsigned short)(u >> 16);
}

__device__ __forceinline__ float fdot2(h2 a, h2 b, float c) {
#if __has_builtin(__builtin_amdgcn_fdot2)
    return __builtin_amdgcn_fdot2(a, b, c, false);
#else
    return (float)a[0] * (float)b[0] + (float)a[1] * (float)b[1] + c;
#endif
}

__device__ __forceinline__ uint32 fas_u(float f) { union { float f; uint32 u; } x; x.f = f; return x.u; }
__device__ __forceinline__ float uas_f(uint32 u) { union { uint32 u; float f; } x; x.u = u; return x.f; }

__device__ __forceinline__ float exp2_n(float x) {
#if __has_builtin(__builtin_amdgcn_exp2f)
    return __builtin_amdgcn_exp2f(x);
#else
    return exp2f(x);
#endif
}
__device__ __forceinline__ float log2_n(float x) {
#if __has_builtin(__builtin_amdgcn_logf)
    return __builtin_amdgcn_logf(x);
#else
    return __log2f(x);
#endif
}
// sign-extended single-bit extract: 0 or 0xFFFFFFFF
__device__ __forceinline__ uint32 bfe1(uint32 v, int off) {
#if __has_builtin(__builtin_amdgcn_sbfe)
    return (uint32)__builtin_amdgcn_sbfe((int)v, off, 1);
#else
    return (uint32)((int)(v << (31 - off)) >> 31);
#endif
}
// unsigned 2-bit extract (the pair's combo index; bits are adjacent)
__device__ __forceinline__ uint32 ubfe2(uint32 v, int off) {
#if __has_builtin(__builtin_amdgcn_ubfe)
    return (uint32)__builtin_amdgcn_ubfe((int)v, off, 2);
#else
    return (v >> off) & 3u;
#endif
}

// x + dpp(y). CTRL: 0xB1 = quad_perm[1,0,3,2], 0x4E = quad_perm[2,3,0,1],
// 0x104 = row_shl:4 — all HW-proven in r3/r4/r5.
template<int CTRL>
__device__ __forceinline__ float dpp_add(float x, float y) {
    union { float f; int i; } a, r;
    a.f = y;
    r.i = __builtin_amdgcn_update_dpp(0, a.i, CTRL, 0xF, 0xF, true);
    return x + r.f;
}

union HU { uint32 u; __half2 hh; h2 v2; };

// ---- K0: fused prep: spin-pack | pair tables (fp16) | zero out ----------
__global__ __launch_bounds__(256) void k_prep(const int* __restrict__ inp,
        const float* __restrict__ eps, u64* __restrict__ bits,
        _Float16* __restrict__ wE, _Float16* __restrict__ cw,
        unsigned short* __restrict__ lrT, float* __restrict__ out) {
    int bid = blockIdx.x;
    if (bid < PACK_BLK) {
        int g = bid * 256 + threadIdx.x;
        const int stride = PACK_BLK * 256;
        #pragma unroll 4
        for (int it = 0; it < PACK_IT; ++it) {
            int v = inp[g];
            u64 m = __ballot(v != 0);
            if ((threadIdx.x & 63) == 0) bits[g >> 6] = m;
            g += stride;
        }
        return;
    }
    bid -= PACK_BLK;
    if (bid < EPS_BLK) {
        int wid = threadIdx.x >> 6, lane = threadIdx.x & 63;
        int m = bid * 4 + wid;
        const float* e0 = eps + (size_t)m * L_N + lane * 16;
        const float* e1 = eps + (size_t)(M_N + m) * L_N + lane * 16;
        float a[16], b[16];
        #pragma unroll
        for (int j = 0; j < 16; j += 4) {
            *(float4*)&a[j] = *(const float4*)&e0[j];
            *(float4*)&b[j] = *(const float4*)&e1[j];
        }
        float local = 1.f;
        #pragma unroll
        for (int j = 0; j < 16; ++j) local *= a[j];
        float sc = local;
        #pragma unroll
        for (int d = 1; d < 64; d <<= 1) {
            float up = __shfl_up(sc, d);
            if (lane >= d) sc *= up;
        }
        float prev = __shfl_up(sc, 1);
        float E = (lane == 0) ? 1.f : prev;
        int i0 = lane * 16;
        float rat_e = 1.f, w_e = 0.f;
        #pragma unroll
        for (int j = 0; j < 16; ++j) {
            float rat = b[j] / a[j];
            float w = E * (a[j] - b[j]);
            lrT[(size_t)m * L_N + i0 + j] = f32_bf16(__log2f(rat));
            int u = (i0 + j) >> 1;
            if ((j & 1) == 0) {
                wE[(size_t)u * M_N + m] = (_Float16)w;
                rat_e = rat; w_e = w;
            } else {
                // super-rows: [0..127]=cmb(combo) | [128..255]=wO(bit0=combo&1)
                _Float16* cr = cw + (size_t)u * 4 * 256;
                float wo1 = w * rat_e;
                cr[0 * 256 + m]       = (_Float16)0.f;
                cr[0 * 256 + 128 + m] = (_Float16)w;
                cr[1 * 256 + m]       = (_Float16)(rat_e - 1.f);
                cr[1 * 256 + 128 + m] = (_Float16)wo1;
                cr[2 * 256 + m]       = (_Float16)(rat - 1.f);
                cr[2 * 256 + 128 + m] = (_Float16)w;
                cr[3 * 256 + m]       = (_Float16)(rat_e * rat - 1.f);
                cr[3 * 256 + 128 + m] = (_Float16)wo1;
            }
            E *= a[j];
        }
        (void)w_e;
        return;
    }
    bid -= EPS_BLK;
    if (bid < ZERO_BLK) {
        out[bid * 256 + threadIdx.x] = 0.f;
    }
}

// ---- K2: MFMA chunk log-sums + f32 cumsum + exp2 -> fp16 excl prefix ----
// blocks [0,1024): prefix at CN granularity; [1024,1056): saturation T.
template<int CN>
__global__ __launch_bounds__(256) void k_slog2(const u64* __restrict__ bits,
        const unsigned short* __restrict__ lrT, _Float16* __restrict__ Rq,
        int* __restrict__ T) {
    if (blockIdx.x >= 1024) {
        int b = (blockIdx.x - 1024) * 256 + threadIdx.x;
        const u64* brow = bits + (size_t)b * 16;
        int n1 = 0, n0 = 0, Tv = 1024;
        for (int wd = 0; wd < 16; ++wd) {
            u64 x = brow[wd];
            int pc = __popcll(x);
            if (n1 + pc < HALF_N && n0 + (64 - pc) < HALF_N) {
                n1 += pc; n0 += 64 - pc;
                continue;
            }
            int found = 0;
            for (int k = 0; k < 64; ++k) {
                if (n1 >= HALF_N || n0 >= HALF_N) { Tv = wd * 64 + k; found = 1; break; }
                int sb = (int)((x >> k) & 1);
                n1 += sb; n0 += 1 - sb;
            }
            if (!found) Tv = (wd + 1) * 64;
            break;
        }
        T[b] = Tv;
        return;
    }
    int btile = blockIdx.x >> 1;
    int half = blockIdx.x & 1;
    int wid = threadIdx.x >> 6, lane = threadIdx.x & 63;
    int col = lane & 15, quad = lane >> 4;
    int m = (half * 4 + wid) * 16 + col;
    int b_row = btile * 16 + col;
    const u64* brow = bits + (size_t)b_row * 16;
    const unsigned short* lrow = lrT + (size_t)m * L_N;

    f32x4 cum = (f32x4){0.f, 0.f, 0.f, 0.f};

    for (int w = 0; w < 16; ++w) {
        u64 wv = brow[w];
        #pragma unroll
        for (int hf = 0; hf < 2; ++hf) {
            if (CN == 32 || hf == 0) {
                int cc = (CN == 32) ? (w * 2 + hf) : w;
                #pragma unroll
                for (int reg = 0; reg < 4; ++reg) {
                    int b = btile * 16 + quad * 4 + reg;
                    Rq[((size_t)cc * B_N + b) * M_N + m] = (_Float16)exp2_n(cum[reg]);
                }
            }
            short8 a;
            #pragma unroll
            for (int j = 0; j < 8; ++j)
                a[j] = (short)((((wv >> (hf * 32 + quad * 8 + j)) & 1) != 0) ? 0x3F80 : 0);
            union { uint4 u; short8 s; } bf;
            bf.u = *(const uint4*)(lrow + w * 64 + hf * 32 + quad * 8);
            cum = __builtin_amdgcn_mfma_f32_16x16x32_bf16(a, bf.s, cum, 0, 0, 0);
        }
    }
}

// ------- K3: main loop — pair-steps, combined [cmb|wO] super-row table ---
// (R12 structure — the measured optimum across R0-R15.) Per pair tt:
// cbo = 2 spin bits. ONE address ad = tt*1024 + cbo*256 + s*16 serves both
// the update row (cmb, at ad) and the odd-dot weight row (wO, at ad+128).
template<int CN>
__global__ __launch_bounds__(256) __attribute__((amdgpu_waves_per_eu(1, 4)))
void k_main(const u64* __restrict__ bits, const _Float16* __restrict__ wE,
        const _Float16* __restrict__ cw, const _Float16* __restrict__ Rq,
        const int* __restrict__ T, float* __restrict__ out) {
    constexpr int CHN = L_N / CN;                // 64 or 32 steps per chunk
    constexpr int CSH = (CN == 16) ? 4 : 5;
    __shared__ _Float16 webuf[16 * M_N];         // 4KB  (16 pairs/phase)
    __shared__ _Float16 cwbuf[16 * 4 * 256];     // 32KB
    int c = blockIdx.x & (CN - 1);
    int bblk = blockIdx.x >> CSH;
    int lane = threadIdx.x & 63, wid = threadIdx.x >> 6;
    int s = lane & 7, grp = lane >> 3;
    int q = s & 3;
    int b0 = bblk * 128 + wid * 32 + grp * 4;

    // prefix load: R2[k][j] = packed pair for b0+(q^k), m = s*16+2j
    HU R2[4][8];
    u64 wb[4];
    const int word0 = (c * CHN) >> 6;            // u64 word holding this chunk
    const int hs0 = ((c * CHN) >> 5) & 1;        // starting 32-bit half
    #pragma unroll
    for (int k = 0; k < 4; ++k) {
        int b = b0 + (q ^ k);
        union { uint4 v[2]; uint32 w[8]; } P;
        const uint4* src = (const uint4*)(Rq + ((size_t)c * B_N + b) * M_N + s * 16);
        P.v[0] = src[0]; P.v[1] = src[1];
        #pragma unroll
        for (int j = 0; j < 8; ++j) R2[k][j].u = P.w[j];
        wb[k] = bits[(size_t)b * 16 + word0];
    }
    int Tb = T[b0 + q];

    const float LOG2E2 = 2.885390082f; // 2*log2(e)
    const float NHL2 = -0.3465735903f; // -0.5*ln2
    float sum = 0.f;
    #pragma unroll
    for (int h = 0; h < CHN / 32; ++h) {
        // stage phase h: 16 pairs (coalesced uint4, linear layout)
        if (h) __syncthreads();
        {
            size_t pbase = (size_t)c * (CHN / 2) + h * 16;
            const uint4* se = (const uint4*)(wE + pbase * M_N);
            const uint4* sc = (const uint4*)(cw + pbase * 4 * 256);
            ((uint4*)webuf)[threadIdx.x] = se[threadIdx.x];
            #pragma unroll
            for (int t = 0; t < 8; ++t)
                ((uint4*)cwbuf)[threadIdx.x + t * 256] = sc[threadIdx.x + t * 256];
        }
        __syncthreads();

        int sh = ((hs0 + h) & 1) * 32;
        uint32 wh[4];
        #pragma unroll
        for (int k = 0; k < 4; ++k) wh[k] = (uint32)(wb[k] >> sh);
        uint32 ows = ~wh[0];                   // own b's word; bit==0 -> flip sign
        int rel = Tb - (c * CHN + h * 32);
        uint32 vmask = (rel <= 0) ? 0u : ((rel >= 32) ? 0xFFFFFFFFu : ((1u << rel) - 1u));

        #pragma unroll 2
        for (int tt = 0; tt < 16; ++tt) {      // 16 pairs = 32 steps
            union U8 { uint4 q4[2]; uint32 w[8]; h2 v2[8]; __half2 hh[8]; };
            U8 WEu;
            const _Float16* web = &webuf[tt * M_N + s * 16];
            WEu.q4[0] = *(const uint4*)web;
            WEu.q4[1] = *((const uint4*)web + 1);

            int pb = tt * 1024 + s * 16;
            int ad[4];
            #pragma unroll
            for (int k = 0; k < 4; ++k)
                ad[k] = pb + (int)(ubfe2(wh[k], 2 * tt) << 8);

            // even dots: shared wE
            float de[4];
            #pragma unroll
            for (int k = 0; k < 4; ++k) {
                float acc = 0.f;
                #pragma unroll
                for (int j = 0; j < 8; ++j) acc = fdot2(R2[k][j].v2, WEu.v2[j], acc);
                de[k] = acc;
            }
            // odd dots: wO half of the selected super-row (+128 elem imm)
            float dd[4];
            #pragma unroll
            for (int k = 0; k < 4; ++k) {
                U8 WOu;
                WOu.q4[0] = *(const uint4*)&cwbuf[ad[k] + 128];
                WOu.q4[1] = *((const uint4*)&cwbuf[ad[k] + 128] + 1);
                float acc = 0.f;
                #pragma unroll
                for (int j = 0; j < 8; ++j) acc = fdot2(R2[k][j].v2, WOu.v2[j], acc);
                dd[k] = acc;
            }
            // butterflies (select-free via k-permute)
            float xe = dpp_add<0xB1>(de[0], de[1]);
            float ye = dpp_add<0xB1>(de[2], de[3]);
            float De = dpp_add<0x4E>(xe, ye);
            De = dpp_add<0x104>(De, De);
            float xo = dpp_add<0xB1>(dd[0], dd[1]);
            float yo = dpp_add<0xB1>(dd[2], dd[3]);
            float Do = dpp_add<0x4E>(xo, yo);
            Do = dpp_add<0x104>(Do, Do);

            // softplus x2 (steps 2tt, 2tt+1), fma-folded tail
            uint32 sg0 = bfe1(ows, 2 * tt) & 0x80000000u;
            float l0 = log2_n(1.f + exp2_n(LOG2E2 * uas_f(fas_u(De) ^ sg0)));
            sum = fmaf(NHL2, uas_f(fas_u(l0) & bfe1(vmask, 2 * tt)), sum);
            uint32 sg1 = bfe1(ows, 2 * tt + 1) & 0x80000000u;
            float l1 = log2_n(1.f + exp2_n(LOG2E2 * uas_f(fas_u(Do) ^ sg1)));
            sum = fmaf(NHL2, uas_f(fas_u(l1) & bfe1(vmask, 2 * tt + 1)), sum);

            // ONE update per pair: R *= 1 + cmb[combo] (cmb half, at ad)
            #pragma unroll
            for (int k = 0; k < 4; ++k) {
                U8 CMu;
                CMu.q4[0] = *(const uint4*)&cwbuf[ad[k]];
                CMu.q4[1] = *((const uint4*)&cwbuf[ad[k]] + 1);
                #pragma unroll
                for (int j = 0; j < 8; ++j)
                    R2[k][j].hh = __hfma2(CMu.hh[j], R2[k][j].hh, R2[k][j].hh);
            }
        }
    }
    if (s < 4) atomicAdd(&out[b0 + s], sum);
}

extern "C" void kernel_launch(void* const* d_in, const int* in_sizes, int n_in,
                              void* d_out, int out_size, void* d_ws, size_t ws_size,
                              hipStream_t stream) {
    const int*   inputs  = (const int*)d_in[0];     // (B, L) int32
    const float* epsilon = (const float*)d_in[1];   // (D, M, L) f32
    float* out = (float*)d_out;                     // (B,) f32

    char* ws = (char*)d_ws;
    _Float16* wE  = (_Float16*)(ws + OFF_WE);
    _Float16* cw  = (_Float16*)(ws + OFF_CW);
    unsigned short* lrT = (unsigned short*)(ws + OFF_LR);
    u64*   bits   = (u64*)  (ws + OFF_BITS);
    int*   T      = (int*)  (ws + OFF_T);
    _Float16* Rq  = (_Float16*)(ws + OFF_RQ);

    k_prep<<<PACK_BLK + EPS_BLK + ZERO_BLK, 256, 0, stream>>>(
        inputs, epsilon, bits, wE, cw, lrT, out);

    // CN=32 needs 64MB Rq; fall back to CN=16 if the workspace can't hold it.
    const size_t need32 = (size_t)OFF_RQ + (size_t)32 * B_N * M_N * 2;
    if (ws_size >= need32) {
        k_slog2<32><<<1024 + 32, 256, 0, stream>>>(bits, lrT, Rq, T);
        k_main<32><<<(B_N / 128) * 32, 256, 0, stream>>>(bits, wE, cw, Rq, T, out);
    } else {
        k_slog2<16><<<1024 + 32, 256, 0, stream>>>(bits, lrT, Rq, T);
        k_main<16><<<(B_N / 128) * 16, 256, 0, stream>>>(bits, wE, cw, Rq, T, out);
    }
}